// Round 2
// baseline (1240.728 us; speedup 1.0000x reference)
//
#include <hip/hip_runtime.h>
#include <math.h>

#define EMB 2048
#define NH 16
#define HD 128
#define BATCH 8
#define SEQ 16
#define KVLEN 4096
#define KSPLIT 8
#define MROWS (BATCH * SEQ) /* 128 */

__device__ __forceinline__ float dot4(float4 a, float4 b) {
  return a.x * b.x + a.y * b.y + a.z * b.z + a.w * b.w;
}

// ---------------------------------------------------------------------------
// Transpose X[R][C] -> XT[C][R], 32x32 tiles.
// ---------------------------------------------------------------------------
__global__ __launch_bounds__(256) void transpose_k(const float* __restrict__ X,
                                                   float* __restrict__ XT,
                                                   int R, int C) {
  __shared__ float t[32][33];
  const int c0 = blockIdx.x * 32, r0 = blockIdx.y * 32;
  const int tx = threadIdx.x & 31, ty = threadIdx.x >> 5;  // ty 0..7
#pragma unroll
  for (int i = 0; i < 4; ++i)
    t[ty + 8 * i][tx] = X[(size_t)(r0 + ty + 8 * i) * C + c0 + tx];
  __syncthreads();
#pragma unroll
  for (int i = 0; i < 4; ++i)
    XT[(size_t)(c0 + ty + 8 * i) * R + r0 + tx] = t[tx][ty + 8 * i];
}

// ---------------------------------------------------------------------------
// GEMM from transposed input: Y[r][d] = sum_c XT[c][r] * W[d][c].
// BM=128 (=MROWS, no m-tiling), BN=64, BK=32, thread tile 8x4, 256 threads.
// Split-K over grid.y (kPartTiles k-tiles per part). Optional fused RoPE
// (linear, commutes with split-K sum).
// Double-buffered LDS, reg-staged (loads issued before compute of prev tile).
// ---------------------------------------------------------------------------
template <bool ROPE>
__global__ __launch_bounds__(256, 2) void gemm_t_k(
    const float* __restrict__ XT,
    const float* __restrict__ W0, const float* __restrict__ W1,
    const float* __restrict__ W2,
    float* __restrict__ Yp, int kPartTiles, int nKTiles, int KP) {
  const int z = blockIdx.z;
  const float* __restrict__ W = (z == 0) ? W0 : (z == 1) ? W1 : W2;
  const int kp = blockIdx.y;
  const int col0 = blockIdx.x * 64;
  const int tid = threadIdx.x;
  const int r0 = (tid & 15) << 3;  // 8 rows
  const int cl = (tid >> 4) << 2;  // 4 cols
  const int t0p = kp * kPartTiles;
  const int t1p = min(nKTiles, t0p + kPartTiles);
  const int nt = t1p - t0p;

  __shared__ float xs[2][32 * 128];
  __shared__ float wt[2][32 * 68];

  float acc[8][4];
#pragma unroll
  for (int i = 0; i < 8; ++i)
#pragma unroll
    for (int jj = 0; jj < 4; ++jj) acc[i][jj] = 0.f;

  const int d0 = tid >> 3, c40 = tid & 7;
  float4 xr0, xr1, xr2, xr3, wr0, wr1;

  auto loadT = [&](int t) {
    const int k0 = (t0p + t) << 5;
    {
      int p = tid;  // f4 index 0..1023 over (i*256+tid)
      int kk = p >> 5, c = p & 31;
      xr0 = *(const float4*)&XT[((size_t)(k0 + kk) << 7) + (c << 2)];
      p = 256 + tid; kk = p >> 5; c = p & 31;
      xr1 = *(const float4*)&XT[((size_t)(k0 + kk) << 7) + (c << 2)];
      p = 512 + tid; kk = p >> 5; c = p & 31;
      xr2 = *(const float4*)&XT[((size_t)(k0 + kk) << 7) + (c << 2)];
      p = 768 + tid; kk = p >> 5; c = p & 31;
      xr3 = *(const float4*)&XT[((size_t)(k0 + kk) << 7) + (c << 2)];
    }
    wr0 = *(const float4*)&W[(size_t)(col0 + d0) * EMB + k0 + (c40 << 2)];
    wr1 = *(const float4*)&W[(size_t)(col0 + 32 + d0) * EMB + k0 + (c40 << 2)];
  };
  auto writeT = [&](int buf) {
    {
      int p = tid; int kk = p >> 5, c = p & 31;
      *(float4*)&xs[buf][(kk << 7) + (c << 2)] = xr0;
      p = 256 + tid; kk = p >> 5; c = p & 31;
      *(float4*)&xs[buf][(kk << 7) + (c << 2)] = xr1;
      p = 512 + tid; kk = p >> 5; c = p & 31;
      *(float4*)&xs[buf][(kk << 7) + (c << 2)] = xr2;
      p = 768 + tid; kk = p >> 5; c = p & 31;
      *(float4*)&xs[buf][(kk << 7) + (c << 2)] = xr3;
    }
#pragma unroll
    for (int t = 0; t < 4; ++t) {
      wt[buf][((c40 << 2) + t) * 68 + d0] = ((const float*)&wr0)[t];
      wt[buf][((c40 << 2) + t) * 68 + 32 + d0] = ((const float*)&wr1)[t];
    }
  };
  auto comp = [&](int buf) {
    const float* xb = &xs[buf][0];
    const float* wb = &wt[buf][0];
#pragma unroll
    for (int kk = 0; kk < 32; ++kk) {
      float4 a0 = *(const float4*)&xb[(kk << 7) + r0];
      float4 a1 = *(const float4*)&xb[(kk << 7) + r0 + 4];
      float4 wv = *(const float4*)&wb[kk * 68 + cl];
      const float* ap = (const float*)&a0;
      const float* wp = (const float*)&wv;
#pragma unroll
      for (int i = 0; i < 4; ++i)
#pragma unroll
        for (int jj = 0; jj < 4; ++jj)
          acc[i][jj] = fmaf(ap[i], wp[jj], acc[i][jj]);
      const float* ap1 = (const float*)&a1;
#pragma unroll
      for (int i = 0; i < 4; ++i)
#pragma unroll
        for (int jj = 0; jj < 4; ++jj)
          acc[4 + i][jj] = fmaf(ap1[i], wp[jj], acc[4 + i][jj]);
    }
  };

  loadT(0);
  writeT(0);
  __syncthreads();
  for (int t = 0; t < nt; ++t) {
    const int cur = t & 1;
    if (t + 1 < nt) loadT(t + 1);
    comp(cur);
    __syncthreads();
    if (t + 1 < nt) writeT(cur ^ 1);
    __syncthreads();
  }

  float* Y = Yp + ((size_t)(z * KP + kp)) * MROWS * EMB;
  if (ROPE && z < 2) {
#pragma unroll
    for (int i = 0; i < 8; ++i) {
      int gr = r0 + i;
      float pos = (float)(gr & 15);
#pragma unroll
      for (int pr = 0; pr < 2; ++pr) {
        int gc = col0 + cl + pr * 2;
        float invf = powf(10000.0f, -(float)(gc & 127) * (1.0f / 128.0f));
        float ang = pos * invf;
        float sn, cs;
        sincosf(ang, &sn, &cs);
        float e = acc[i][pr * 2], o = acc[i][pr * 2 + 1];
        Y[(size_t)gr * EMB + gc] = e * cs - o * sn;
        Y[(size_t)gr * EMB + gc + 1] = e * sn + o * cs;
      }
    }
  } else {
#pragma unroll
    for (int i = 0; i < 8; ++i)
#pragma unroll
      for (int jj = 0; jj < 4; ++jj)
        Y[(size_t)(r0 + i) * EMB + col0 + cl + jj] = acc[i][jj];
  }
}

// ---------------------------------------------------------------------------
// sum 3 split-K parts for each of q,k,v
// ---------------------------------------------------------------------------
__global__ __launch_bounds__(256) void sum3_k(const float* __restrict__ parts,
                                              float* __restrict__ y0,
                                              float* __restrict__ y1,
                                              float* __restrict__ y2) {
  const size_t idx = (size_t)blockIdx.x * 256 + threadIdx.x;  // f4 index
  const size_t n4 = 65536;
  const float4* p = (const float4*)parts;
  float* outs[3] = {y0, y1, y2};
#pragma unroll
  for (int z = 0; z < 3; ++z) {
    float4 a = p[((size_t)z * 3 + 0) * n4 + idx];
    float4 b2 = p[((size_t)z * 3 + 1) * n4 + idx];
    float4 c = p[((size_t)z * 3 + 2) * n4 + idx];
    float4 s = make_float4(a.x + b2.x + c.x, a.y + b2.y + c.y,
                           a.z + b2.z + c.z, a.w + b2.w + c.w);
    ((float4*)outs[z])[idx] = s;
  }
}

// ---------------------------------------------------------------------------
// sum 8 split-K parts + bias -> final output
// ---------------------------------------------------------------------------
__global__ __launch_bounds__(256) void sum8_bias_k(const float* __restrict__ parts,
                                                   const float* __restrict__ bo,
                                                   float* __restrict__ out) {
  const size_t idx = (size_t)blockIdx.x * 256 + threadIdx.x;  // f4 index
  float4 s = *(const float4*)&bo[(idx << 2) & 2047];
  const float4* p = (const float4*)parts;
#pragma unroll
  for (int k = 0; k < 8; ++k) {
    float4 v = p[(size_t)k * 65536 + idx];
    s.x += v.x; s.y += v.y; s.z += v.z; s.w += v.w;
  }
  ((float4*)out)[idx] = s;
}

// ---------------------------------------------------------------------------
// Flash-decoding attention partial. Grid (KSPLIT, NH, BATCH), 256 threads.
// wave = 4 q-rows; lane = (kslot 0..15, g 0..3); thread owns 4 keys x 32-d.
// K/V staged in LDS with XOR swizzle (16B-chunk c at slot (c&24)|((c^(row>>2))&7)).
// Q read from global (L1-hot). Softmax & P in registers via shfl. O in 128
// regs/thread, shfl-reduced over kslot at the end.
// ---------------------------------------------------------------------------
__global__ __launch_bounds__(256, 2) void attn_partial_k(
    const float* __restrict__ q, const float* __restrict__ knew,
    const float* __restrict__ vnew, const float* __restrict__ ck,
    const float* __restrict__ cv, const int* __restrict__ sp_ptr,
    float* __restrict__ po, float* __restrict__ pm, float* __restrict__ pl) {
  const int j = blockIdx.x, h = blockIdx.y, b = blockIdx.z;
  const int tid = threadIdx.x;
  const int wid = tid >> 6;
  const int lane = tid & 63;
  const int kslot = lane & 15;
  const int g = lane >> 4;
  const int sp = *sp_ptr;
  const int L = sp + SEQ;
  const int chunk = (L + KSPLIT - 1) / KSPLIT;
  const int c0 = j * chunk;
  const int c1 = min(L, c0 + chunk);

  __shared__ float kt[64 * 128];
  __shared__ float vt[64 * 128];

  float acc[4][32];
#pragma unroll
  for (int qq = 0; qq < 4; ++qq)
#pragma unroll
    for (int d = 0; d < 32; ++d) acc[qq][d] = 0.f;
  float m[4] = {-1e30f, -1e30f, -1e30f, -1e30f};
  float l[4] = {0.f, 0.f, 0.f, 0.f};

  const float* qbase = q + (size_t)(b * SEQ + (wid << 2)) * EMB + h * HD + (g << 5);
  const float qscale = 0.08838834764831845f;  // 1/sqrt(128)

  for (int t0 = c0; t0 < c1; t0 += 64) {
    __syncthreads();  // previous tile's LDS reads done
    // ---- stage K,V tile (reg -> swizzled LDS) ----
    {
      float4 kr[8], vr[8];
#pragma unroll
      for (int i = 0; i < 8; ++i) {
        int p = (i << 8) + tid;  // data chunk 0..2047
        int row = p >> 5, c = p & 31;
        int gk = t0 + row;
        int gkE = min(gk, c1 - 1);
        size_t off;
        const float *sk, *sv;
        if (gkE < sp) {
          off = ((size_t)b * KVLEN + gkE) * EMB + h * HD + ((size_t)c << 2);
          sk = ck + off; sv = cv + off;
        } else {
          off = ((size_t)b * SEQ + (gkE - sp)) * EMB + h * HD + ((size_t)c << 2);
          sk = knew + off; sv = vnew + off;
        }
        kr[i] = *(const float4*)sk;
        vr[i] = *(const float4*)sv;
      }
#pragma unroll
      for (int i = 0; i < 8; ++i) {
        int p = (i << 8) + tid;
        int row = p >> 5, c = p & 31;
        int sl = (c & 24) | ((c ^ (row >> 2)) & 7);
        int a = ((row << 5) + sl) << 2;
        *(float4*)&kt[a] = kr[i];
        *(float4*)&vt[a] = vr[i];
      }
    }
    __syncthreads();  // tile staged

    // ---- scores: thread keys {4*kslot+i}, d-slice g*32..+31 ----
    float p4[4][4];
#pragma unroll
    for (int i = 0; i < 4; ++i) {
      const int row = (kslot << 2) + i;
      const int fr = kslot & 7;
      const int rb = row << 7;
      float4 K8[8];
#pragma unroll
      for (int jj = 0; jj < 8; ++jj) {
        int cc = (g << 3) | (jj ^ fr);
        K8[jj] = *(const float4*)&kt[rb + (cc << 2)];
      }
#pragma unroll
      for (int qq = 0; qq < 4; ++qq) {
        const float* qp = qbase + (size_t)qq * EMB;
        float s = 0.f;
#pragma unroll
        for (int jj = 0; jj < 8; ++jj) {
          float4 qv = *(const float4*)&qp[jj << 2];
          s += dot4(K8[jj], qv);
        }
        p4[qq][i] = s;
      }
    }
    // ---- reduce over g, mask, online softmax (all in regs) ----
#pragma unroll
    for (int qq = 0; qq < 4; ++qq) {
#pragma unroll
      for (int i = 0; i < 4; ++i) {
        float v = p4[qq][i];
        v += __shfl_xor(v, 16);
        v += __shfl_xor(v, 32);
        v *= qscale;
        if (t0 + (kslot << 2) + i >= c1) v = -3.0e38f;
        p4[qq][i] = v;
      }
      float tm = fmaxf(fmaxf(p4[qq][0], p4[qq][1]), fmaxf(p4[qq][2], p4[qq][3]));
      tm = fmaxf(tm, __shfl_xor(tm, 1));
      tm = fmaxf(tm, __shfl_xor(tm, 2));
      tm = fmaxf(tm, __shfl_xor(tm, 4));
      tm = fmaxf(tm, __shfl_xor(tm, 8));
      float mn = fmaxf(m[qq], tm);
      float sc = __expf(m[qq] - mn);
      float ls = 0.f;
#pragma unroll
      for (int i = 0; i < 4; ++i) {
        float pe = __expf(p4[qq][i] - mn);
        p4[qq][i] = pe;
        ls += pe;
      }
      ls += __shfl_xor(ls, 1);
      ls += __shfl_xor(ls, 2);
      ls += __shfl_xor(ls, 4);
      ls += __shfl_xor(ls, 8);
      l[qq] = l[qq] * sc + ls;
      m[qq] = mn;
#pragma unroll
      for (int d = 0; d < 32; ++d) acc[qq][d] *= sc;
    }
    // ---- PV: same keys, V d-slice ----
#pragma unroll
    for (int i = 0; i < 4; ++i) {
      const int row = (kslot << 2) + i;
      const int fr = kslot & 7;
      const int rb = row << 7;
      float4 V8[8];
#pragma unroll
      for (int jj = 0; jj < 8; ++jj) {
        int cc = (g << 3) | (jj ^ fr);
        V8[jj] = *(const float4*)&vt[rb + (cc << 2)];
      }
#pragma unroll
      for (int qq = 0; qq < 4; ++qq) {
        float pv = p4[qq][i];
#pragma unroll
        for (int jj = 0; jj < 8; ++jj) {
          acc[qq][(jj << 2) + 0] = fmaf(pv, V8[jj].x, acc[qq][(jj << 2) + 0]);
          acc[qq][(jj << 2) + 1] = fmaf(pv, V8[jj].y, acc[qq][(jj << 2) + 1]);
          acc[qq][(jj << 2) + 2] = fmaf(pv, V8[jj].z, acc[qq][(jj << 2) + 2]);
          acc[qq][(jj << 2) + 3] = fmaf(pv, V8[jj].w, acc[qq][(jj << 2) + 3]);
        }
      }
    }
  }

  // ---- reduce O over kslot lanes; write partials ----
#pragma unroll
  for (int qq = 0; qq < 4; ++qq)
#pragma unroll
    for (int d = 0; d < 32; ++d) {
      float v = acc[qq][d];
      v += __shfl_xor(v, 1);
      v += __shfl_xor(v, 2);
      v += __shfl_xor(v, 4);
      v += __shfl_xor(v, 8);
      acc[qq][d] = v;
    }
  const size_t pair = (size_t)(b * NH + h);
  const size_t pb = (pair * KSPLIT + j) * SEQ + (wid << 2);
  if (kslot == 0) {
#pragma unroll
    for (int qq = 0; qq < 4; ++qq)
#pragma unroll
      for (int jj = 0; jj < 8; ++jj)
        *(float4*)&po[(pb + qq) * HD + (g << 5) + (jj << 2)] =
            make_float4(acc[qq][(jj << 2)], acc[qq][(jj << 2) + 1],
                        acc[qq][(jj << 2) + 2], acc[qq][(jj << 2) + 3]);
  }
  if (lane == 0) {
#pragma unroll
    for (int qq = 0; qq < 4; ++qq) {
      pm[pb + qq] = m[qq];
      pl[pb + qq] = l[qq];
    }
  }
}

// ---------------------------------------------------------------------------
// Combine KSPLIT partials -> attnT [EMB][MROWS] (transposed for Wo GEMM).
// ---------------------------------------------------------------------------
__global__ __launch_bounds__(256) void combine_k(const float* __restrict__ po,
                                                 const float* __restrict__ pm,
                                                 const float* __restrict__ pl,
                                                 float* __restrict__ attnT) {
  const int pair = blockIdx.x;
  const int b = pair >> 4, h = pair & 15;
  const int tid = threadIdx.x;
  const int d = tid & 127, gq = tid >> 7;
#pragma unroll
  for (int qi = 0; qi < 8; ++qi) {
    int qq = gq * 8 + qi;
    float mj[KSPLIT], lj[KSPLIT];
    float Mx = -1e30f;
#pragma unroll
    for (int jj = 0; jj < KSPLIT; ++jj) {
      mj[jj] = pm[((size_t)pair * KSPLIT + jj) * SEQ + qq];
      lj[jj] = pl[((size_t)pair * KSPLIT + jj) * SEQ + qq];
      Mx = fmaxf(Mx, mj[jj]);
    }
    float Ls = 0.f, o = 0.f;
#pragma unroll
    for (int jj = 0; jj < KSPLIT; ++jj) {
      float w = __expf(mj[jj] - Mx);
      Ls += lj[jj] * w;
      o += po[(((size_t)pair * KSPLIT + jj) * SEQ + qq) * HD + d] * w;
    }
    attnT[(size_t)(h * HD + d) * MROWS + b * SEQ + qq] = o / Ls;
  }
}

// ---------------------------------------------------------------------------
extern "C" void kernel_launch(void* const* d_in, const int* in_sizes, int n_in,
                              void* d_out, int out_size, void* d_ws,
                              size_t ws_size, hipStream_t stream) {
  const float* x = (const float*)d_in[0];
  const float* Wq = (const float*)d_in[1];
  const float* Wk = (const float*)d_in[2];
  const float* Wv = (const float*)d_in[3];
  const float* Wo = (const float*)d_in[4];
  const float* bo = (const float*)d_in[5];
  const float* ck = (const float*)d_in[6];
  const float* cv = (const float*)d_in[7];
  const int* sp = (const int*)d_in[8];
  float* out = (float*)d_out;

  float* ws = (float*)d_ws;
  const size_t U = 262144;  // 128*2048
  float* XT = ws;                  // [0,1)
  float* yq = ws + U * 1;
  float* yk = ws + U * 2;
  float* yv = ws + U * 3;
  float* attnT = ws + U * 4;
  float* qkvParts = ws + U * 5;    // [5,14): 3z x 3kp
  float* woParts = ws + U * 14;    // [14,22): 8kp
  float* po = ws + U * 22;         // [22,30): 128*8*16*128
  float* pm = ws + U * 30;
  float* pl = ws + U * 30 + 16384;

  // 1) transpose x -> XT [2048][128]
  transpose_k<<<dim3(64, 4), 256, 0, stream>>>(x, XT, MROWS, EMB);

  // 2) QKV projection (split-K=3) with fused RoPE on q,k parts
  gemm_t_k<true><<<dim3(32, 3, 3), 256, 0, stream>>>(XT, Wq, Wk, Wv,
                                                     qkvParts, 22, 64, 3);

  // 3) sum split-K parts
  sum3_k<<<dim3(256), 256, 0, stream>>>(qkvParts, yq, yk, yv);

  // 4) flash-decoding attention partials
  attn_partial_k<<<dim3(KSPLIT, NH, BATCH), 256, 0, stream>>>(
      yq, yk, yv, ck, cv, sp, po, pm, pl);

  // 5) combine -> attnT (transposed)
  combine_k<<<dim3(BATCH * NH), 256, 0, stream>>>(po, pm, pl, attnT);

  // 6) output projection (split-K=8)
  gemm_t_k<false><<<dim3(32, 8, 1), 256, 0, stream>>>(attnT, Wo, Wo, Wo,
                                                      woParts, 8, 64, 8);

  // 7) sum parts + bias -> out
  sum8_bias_k<<<dim3(256), 256, 0, stream>>>(woParts, bo, out);

  (void)in_sizes; (void)n_in; (void)out_size; (void)ws_size;
}

// Round 3
// 568.277 us; speedup vs baseline: 2.1833x; 2.1833x over previous
//
#include <hip/hip_runtime.h>
#include <math.h>

#define EMB 2048
#define NH 16
#define HD 128
#define BATCH 8
#define SEQ 16
#define KVLEN 4096
#define KSPLIT 8
#define MROWS (BATCH * SEQ) /* 128 */

__device__ __forceinline__ float dot4(float4 a, float4 b) {
  return a.x * b.x + a.y * b.y + a.z * b.z + a.w * b.w;
}

// ---------------------------------------------------------------------------
// fp32 GEMM: Ypart[r][d] = sum_{c in k-slice} X[r][c] * W[d][c].
// Grid (32 colblocks, 8 k-parts, NMAT). 256 threads = 4 waves.
// Block tile: 128 rows x 64 cols, K-slice 256 (8 tiles of 32).
// Lane tile: 8 rows x 4 cols. W staged reg->LDS (dbuf, XOR-swizzled,
// conflict-free b128 reads). X read per-lane from global (L2-resident).
// No address-taken vector locals, no lambdas.
// ---------------------------------------------------------------------------
__global__ __launch_bounds__(256) void gemm_f32(
    const float* __restrict__ X, const float* __restrict__ W0,
    const float* __restrict__ W1, const float* __restrict__ W2,
    float* __restrict__ Yp) {
  const int z = blockIdx.z;
  const float* __restrict__ W = (z == 0) ? W0 : (z == 1) ? W1 : W2;
  const int kp = blockIdx.y;       // 0..7
  const int c0 = blockIdx.x * 64;  // col block
  const int k0 = kp * 256;         // k-slice start
  const int tid = threadIdx.x;
  const int lane = tid & 63;
  const int wid = tid >> 6;

  const int colg = lane & 15;                     // lane cols: c0+4*colg+cc
  const int rbase = wid * 32 + (lane >> 4) * 8;   // lane rows: rbase..rbase+7
  const int perm = lane & 7;                      // read-side XOR key

  __shared__ float wt[2][64 * 32];

  float acc[8][4];
#pragma unroll
  for (int i = 0; i < 8; ++i)
#pragma unroll
    for (int c = 0; c < 4; ++c) acc[i][c] = 0.f;

  // staging role: chunks tid (c<32) and tid+256 (c>=32); chunk=(c,k4)
  const int sc0 = tid >> 3, sk = tid & 7;
  const int sc1 = 32 + sc0;
  const float* wsrc0 = &W[(size_t)(c0 + sc0) * EMB + k0 + sk * 4];
  const float* wsrc1 = &W[(size_t)(c0 + sc1) * EMB + k0 + sk * 4];
  const int wo0 = sc0 * 32 + 4 * (sk ^ ((sc0 >> 2) & 7));
  const int wo1 = sc1 * 32 + 4 * (sk ^ ((sc1 >> 2) & 7));

  const float* xbase = X + (size_t)rbase * EMB + k0;

  // prologue: stage tile 0, issue loads for tile 1
  float4 s0 = *(const float4*)(wsrc0);
  float4 s1 = *(const float4*)(wsrc1);
  *(float4*)&wt[0][wo0] = s0;
  *(float4*)&wt[0][wo1] = s1;
  float4 n0 = *(const float4*)(wsrc0 + 32);
  float4 n1 = *(const float4*)(wsrc1 + 32);
  __syncthreads();

  for (int t = 0; t < 8; ++t) {
    const int buf = t & 1;
    const float* wb = &wt[buf][0];
    const int xoff = t * 32;
#pragma unroll
    for (int k4 = 0; k4 < 8; ++k4) {
      float4 xv[8];
#pragma unroll
      for (int i = 0; i < 8; ++i)
        xv[i] = *(const float4*)&xbase[(size_t)i * EMB + xoff + k4 * 4];
      float4 wv[4];
#pragma unroll
      for (int c = 0; c < 4; ++c)
        wv[c] = *(const float4*)&wb[(4 * colg + c) * 32 + 4 * (k4 ^ perm)];
#pragma unroll
      for (int i = 0; i < 8; ++i)
#pragma unroll
        for (int c = 0; c < 4; ++c)
          acc[i][c] = fmaf(xv[i].w, wv[c].w,
                      fmaf(xv[i].z, wv[c].z,
                      fmaf(xv[i].y, wv[c].y,
                      fmaf(xv[i].x, wv[c].x, acc[i][c]))));
    }
    if (t < 7) {
      *(float4*)&wt[buf ^ 1][wo0] = n0;
      *(float4*)&wt[buf ^ 1][wo1] = n1;
      if (t < 6) {
        n0 = *(const float4*)(wsrc0 + (t + 2) * 32);
        n1 = *(const float4*)(wsrc1 + (t + 2) * 32);
      }
    }
    __syncthreads();
  }

  float* yout = Yp + ((size_t)(z * 8 + kp) * MROWS + rbase) * EMB + c0 + colg * 4;
#pragma unroll
  for (int i = 0; i < 8; ++i)
    *(float4*)&yout[(size_t)i * EMB] =
        make_float4(acc[i][0], acc[i][1], acc[i][2], acc[i][3]);
}

// ---------------------------------------------------------------------------
// Sum 8 split-K parts per matrix; apply RoPE to q,k (z=0,1); v plain.
// ---------------------------------------------------------------------------
__global__ __launch_bounds__(256) void sum_qkv_rope_k(
    const float* __restrict__ parts, float* __restrict__ yq,
    float* __restrict__ yk, float* __restrict__ yv) {
  const int idx4 = blockIdx.x * 256 + threadIdx.x;  // float4 index, 0..65535
  const int idx = idx4 << 2;
  const int row = idx >> 11;
  const int col = idx & 2047;
  const float s = (float)(row & 15);
  const int hd = col & 127;  // even
  const float a0 = s * powf(10000.0f, -(float)hd * (1.0f / 128.0f));
  const float a1 = s * powf(10000.0f, -(float)(hd + 2) * (1.0f / 128.0f));
  float sn0, cs0, sn1, cs1;
  sincosf(a0, &sn0, &cs0);
  sincosf(a1, &sn1, &cs1);
  const float4* p = (const float4*)parts;
  float* outs[3] = {yq, yk, yv};
#pragma unroll
  for (int z = 0; z < 3; ++z) {
    float4 v = make_float4(0.f, 0.f, 0.f, 0.f);
#pragma unroll
    for (int k = 0; k < 8; ++k) {
      float4 a = p[((size_t)(z * 8 + k)) * 65536 + idx4];
      v.x += a.x; v.y += a.y; v.z += a.z; v.w += a.w;
    }
    if (z < 2) {
      float4 r;
      r.x = v.x * cs0 - v.y * sn0;
      r.y = v.x * sn0 + v.y * cs0;
      r.z = v.z * cs1 - v.w * sn1;
      r.w = v.z * sn1 + v.w * cs1;
      v = r;
    }
    ((float4*)outs[z])[idx4] = v;
  }
}

// ---------------------------------------------------------------------------
// sum 8 split-K parts + bias -> final output
// ---------------------------------------------------------------------------
__global__ __launch_bounds__(256) void sum8_bias_k(const float* __restrict__ parts,
                                                   const float* __restrict__ bo,
                                                   float* __restrict__ out) {
  const size_t idx = (size_t)blockIdx.x * 256 + threadIdx.x;  // f4 index
  float4 s = *(const float4*)&bo[(idx << 2) & 2047];
  const float4* p = (const float4*)parts;
#pragma unroll
  for (int k = 0; k < 8; ++k) {
    float4 v = p[(size_t)k * 65536 + idx];
    s.x += v.x; s.y += v.y; s.z += v.z; s.w += v.w;
  }
  ((float4*)out)[idx] = s;
}

// ---------------------------------------------------------------------------
// Flash-decoding attention partial. Grid (KSPLIT, NH, BATCH), 256 threads.
// (unchanged from R2 — passed validation)
// ---------------------------------------------------------------------------
__global__ __launch_bounds__(256, 2) void attn_partial_k(
    const float* __restrict__ q, const float* __restrict__ knew,
    const float* __restrict__ vnew, const float* __restrict__ ck,
    const float* __restrict__ cv, const int* __restrict__ sp_ptr,
    float* __restrict__ po, float* __restrict__ pm, float* __restrict__ pl) {
  const int j = blockIdx.x, h = blockIdx.y, b = blockIdx.z;
  const int tid = threadIdx.x;
  const int wid = tid >> 6;
  const int lane = tid & 63;
  const int kslot = lane & 15;
  const int g = lane >> 4;
  const int sp = *sp_ptr;
  const int L = sp + SEQ;
  const int chunk = (L + KSPLIT - 1) / KSPLIT;
  const int c0 = j * chunk;
  const int c1 = min(L, c0 + chunk);

  __shared__ float kt[64 * 128];
  __shared__ float vt[64 * 128];

  float acc[4][32];
#pragma unroll
  for (int qq = 0; qq < 4; ++qq)
#pragma unroll
    for (int d = 0; d < 32; ++d) acc[qq][d] = 0.f;
  float m[4] = {-1e30f, -1e30f, -1e30f, -1e30f};
  float l[4] = {0.f, 0.f, 0.f, 0.f};

  const float* qbase = q + (size_t)(b * SEQ + (wid << 2)) * EMB + h * HD + (g << 5);
  const float qscale = 0.08838834764831845f;  // 1/sqrt(128)

  for (int t0 = c0; t0 < c1; t0 += 64) {
    __syncthreads();
    {
      float4 kr[8], vr[8];
#pragma unroll
      for (int i = 0; i < 8; ++i) {
        int p = (i << 8) + tid;
        int row = p >> 5, c = p & 31;
        int gk = t0 + row;
        int gkE = min(gk, c1 - 1);
        size_t off;
        const float *sk, *sv;
        if (gkE < sp) {
          off = ((size_t)b * KVLEN + gkE) * EMB + h * HD + ((size_t)c << 2);
          sk = ck + off; sv = cv + off;
        } else {
          off = ((size_t)b * SEQ + (gkE - sp)) * EMB + h * HD + ((size_t)c << 2);
          sk = knew + off; sv = vnew + off;
        }
        kr[i] = *(const float4*)sk;
        vr[i] = *(const float4*)sv;
      }
#pragma unroll
      for (int i = 0; i < 8; ++i) {
        int p = (i << 8) + tid;
        int row = p >> 5, c = p & 31;
        int sl = (c & 24) | ((c ^ (row >> 2)) & 7);
        int a = ((row << 5) + sl) << 2;
        *(float4*)&kt[a] = kr[i];
        *(float4*)&vt[a] = vr[i];
      }
    }
    __syncthreads();

    float p4[4][4];
#pragma unroll
    for (int i = 0; i < 4; ++i) {
      const int row = (kslot << 2) + i;
      const int fr = kslot & 7;
      const int rb = row << 7;
      float4 K8[8];
#pragma unroll
      for (int jj = 0; jj < 8; ++jj) {
        int cc = (g << 3) | (jj ^ fr);
        K8[jj] = *(const float4*)&kt[rb + (cc << 2)];
      }
#pragma unroll
      for (int qq = 0; qq < 4; ++qq) {
        const float* qp = qbase + (size_t)qq * EMB;
        float s = 0.f;
#pragma unroll
        for (int jj = 0; jj < 8; ++jj) {
          float4 qv = *(const float4*)&qp[jj << 2];
          s += dot4(K8[jj], qv);
        }
        p4[qq][i] = s;
      }
    }
#pragma unroll
    for (int qq = 0; qq < 4; ++qq) {
#pragma unroll
      for (int i = 0; i < 4; ++i) {
        float v = p4[qq][i];
        v += __shfl_xor(v, 16);
        v += __shfl_xor(v, 32);
        v *= qscale;
        if (t0 + (kslot << 2) + i >= c1) v = -3.0e38f;
        p4[qq][i] = v;
      }
      float tm = fmaxf(fmaxf(p4[qq][0], p4[qq][1]), fmaxf(p4[qq][2], p4[qq][3]));
      tm = fmaxf(tm, __shfl_xor(tm, 1));
      tm = fmaxf(tm, __shfl_xor(tm, 2));
      tm = fmaxf(tm, __shfl_xor(tm, 4));
      tm = fmaxf(tm, __shfl_xor(tm, 8));
      float mn = fmaxf(m[qq], tm);
      float sc = __expf(m[qq] - mn);
      float ls = 0.f;
#pragma unroll
      for (int i = 0; i < 4; ++i) {
        float pe = __expf(p4[qq][i] - mn);
        p4[qq][i] = pe;
        ls += pe;
      }
      ls += __shfl_xor(ls, 1);
      ls += __shfl_xor(ls, 2);
      ls += __shfl_xor(ls, 4);
      ls += __shfl_xor(ls, 8);
      l[qq] = l[qq] * sc + ls;
      m[qq] = mn;
#pragma unroll
      for (int d = 0; d < 32; ++d) acc[qq][d] *= sc;
    }
#pragma unroll
    for (int i = 0; i < 4; ++i) {
      const int row = (kslot << 2) + i;
      const int fr = kslot & 7;
      const int rb = row << 7;
      float4 V8[8];
#pragma unroll
      for (int jj = 0; jj < 8; ++jj) {
        int cc = (g << 3) | (jj ^ fr);
        V8[jj] = *(const float4*)&vt[rb + (cc << 2)];
      }
#pragma unroll
      for (int qq = 0; qq < 4; ++qq) {
        float pv = p4[qq][i];
#pragma unroll
        for (int jj = 0; jj < 8; ++jj) {
          acc[qq][(jj << 2) + 0] = fmaf(pv, V8[jj].x, acc[qq][(jj << 2) + 0]);
          acc[qq][(jj << 2) + 1] = fmaf(pv, V8[jj].y, acc[qq][(jj << 2) + 1]);
          acc[qq][(jj << 2) + 2] = fmaf(pv, V8[jj].z, acc[qq][(jj << 2) + 2]);
          acc[qq][(jj << 2) + 3] = fmaf(pv, V8[jj].w, acc[qq][(jj << 2) + 3]);
        }
      }
    }
  }

#pragma unroll
  for (int qq = 0; qq < 4; ++qq)
#pragma unroll
    for (int d = 0; d < 32; ++d) {
      float v = acc[qq][d];
      v += __shfl_xor(v, 1);
      v += __shfl_xor(v, 2);
      v += __shfl_xor(v, 4);
      v += __shfl_xor(v, 8);
      acc[qq][d] = v;
    }
  const size_t pair = (size_t)(b * NH + h);
  const size_t pb = (pair * KSPLIT + j) * SEQ + (wid << 2);
  if (kslot == 0) {
#pragma unroll
    for (int qq = 0; qq < 4; ++qq)
#pragma unroll
      for (int jj = 0; jj < 8; ++jj)
        *(float4*)&po[(pb + qq) * HD + (g << 5) + (jj << 2)] =
            make_float4(acc[qq][(jj << 2)], acc[qq][(jj << 2) + 1],
                        acc[qq][(jj << 2) + 2], acc[qq][(jj << 2) + 3]);
  }
  if (lane == 0) {
#pragma unroll
    for (int qq = 0; qq < 4; ++qq) {
      pm[pb + qq] = m[qq];
      pl[pb + qq] = l[qq];
    }
  }
}

// ---------------------------------------------------------------------------
// Combine KSPLIT partials -> attention output (B,S,H*D) row-major.
// ---------------------------------------------------------------------------
__global__ __launch_bounds__(256) void combine_k(const float* __restrict__ po,
                                                 const float* __restrict__ pm,
                                                 const float* __restrict__ pl,
                                                 float* __restrict__ attn) {
  const int pair = blockIdx.x;
  const int b = pair >> 4, h = pair & 15;
  const int tid = threadIdx.x;
  const int d = tid & 127, gq = tid >> 7;
#pragma unroll
  for (int qi = 0; qi < 8; ++qi) {
    int qq = gq * 8 + qi;
    float mj[KSPLIT], lj[KSPLIT];
    float Mx = -1e30f;
#pragma unroll
    for (int jj = 0; jj < KSPLIT; ++jj) {
      mj[jj] = pm[((size_t)pair * KSPLIT + jj) * SEQ + qq];
      lj[jj] = pl[((size_t)pair * KSPLIT + jj) * SEQ + qq];
      Mx = fmaxf(Mx, mj[jj]);
    }
    float Ls = 0.f, o = 0.f;
#pragma unroll
    for (int jj = 0; jj < KSPLIT; ++jj) {
      float w = __expf(mj[jj] - Mx);
      Ls += lj[jj] * w;
      o += po[(((size_t)pair * KSPLIT + jj) * SEQ + qq) * HD + d] * w;
    }
    attn[(size_t)(b * SEQ + qq) * EMB + h * HD + d] = o / Ls;
  }
}

// ---------------------------------------------------------------------------
extern "C" void kernel_launch(void* const* d_in, const int* in_sizes, int n_in,
                              void* d_out, int out_size, void* d_ws,
                              size_t ws_size, hipStream_t stream) {
  const float* x = (const float*)d_in[0];
  const float* Wq = (const float*)d_in[1];
  const float* Wk = (const float*)d_in[2];
  const float* Wv = (const float*)d_in[3];
  const float* Wo = (const float*)d_in[4];
  const float* bo = (const float*)d_in[5];
  const float* ck = (const float*)d_in[6];
  const float* cv = (const float*)d_in[7];
  const int* sp = (const int*)d_in[8];
  float* out = (float*)d_out;

  float* ws = (float*)d_ws;
  const size_t U = 262144;  // 128*2048 floats
  float* yq = ws;
  float* yk = ws + U * 1;
  float* yv = ws + U * 2;
  float* attn = ws + U * 3;
  float* qkvParts = ws + U * 4;   // 3 mats x 8 parts -> [4,28)
  float* woParts = ws + U * 28;   // 8 parts -> [28,36)
  float* po = ws + U * 36;        // 128 pairs x 8 x 16 x 128 = 8U -> [36,44)
  float* pm = ws + U * 44;
  float* pl = ws + U * 44 + 16384;

  // 1) QKV projection, split-K=8
  gemm_f32<<<dim3(32, 8, 3), 256, 0, stream>>>(x, Wq, Wk, Wv, qkvParts);

  // 2) sum parts + RoPE on q,k
  sum_qkv_rope_k<<<dim3(256), 256, 0, stream>>>(qkvParts, yq, yk, yv);

  // 3) flash-decoding attention partials
  attn_partial_k<<<dim3(KSPLIT, NH, BATCH), 256, 0, stream>>>(
      yq, yk, yv, ck, cv, sp, po, pm, pl);

  // 4) combine -> attn (row-major)
  combine_k<<<dim3(BATCH * NH), 256, 0, stream>>>(po, pm, pl, attn);

  // 5) output projection, split-K=8
  gemm_f32<<<dim3(32, 8, 1), 256, 0, stream>>>(attn, Wo, Wo, Wo, woParts);

  // 6) sum parts + bias -> out
  sum8_bias_k<<<dim3(256), 256, 0, stream>>>(woParts, bo, out);

  (void)in_sizes; (void)n_in; (void)out_size; (void)ws_size;
}

// Round 4
// 292.147 us; speedup vs baseline: 4.2469x; 1.9452x over previous
//
#include <hip/hip_runtime.h>
#include <math.h>

#define EMB 2048
#define NH 16
#define HD 128
#define BATCH 8
#define SEQ 16
#define KVLEN 4096
#define KSPLIT 8
#define MROWS (BATCH * SEQ) /* 128 */

__device__ __forceinline__ float dot4(float4 a, float4 b) {
  return a.x * b.x + a.y * b.y + a.z * b.z + a.w * b.w;
}

// ---------------------------------------------------------------------------
// fp32 GEMM: Ypart[r][d] = sum_{c in k-slice} X[r][c] * W[d][c].
// (unchanged from R3 — working)
// ---------------------------------------------------------------------------
__global__ __launch_bounds__(256) void gemm_f32(
    const float* __restrict__ X, const float* __restrict__ W0,
    const float* __restrict__ W1, const float* __restrict__ W2,
    float* __restrict__ Yp) {
  const int z = blockIdx.z;
  const float* __restrict__ W = (z == 0) ? W0 : (z == 1) ? W1 : W2;
  const int kp = blockIdx.y;       // 0..7
  const int c0 = blockIdx.x * 64;  // col block
  const int k0 = kp * 256;         // k-slice start
  const int tid = threadIdx.x;
  const int lane = tid & 63;
  const int wid = tid >> 6;

  const int colg = lane & 15;
  const int rbase = wid * 32 + (lane >> 4) * 8;
  const int perm = lane & 7;

  __shared__ float wt[2][64 * 32];

  float acc[8][4];
#pragma unroll
  for (int i = 0; i < 8; ++i)
#pragma unroll
    for (int c = 0; c < 4; ++c) acc[i][c] = 0.f;

  const int sc0 = tid >> 3, sk = tid & 7;
  const int sc1 = 32 + sc0;
  const float* wsrc0 = &W[(size_t)(c0 + sc0) * EMB + k0 + sk * 4];
  const float* wsrc1 = &W[(size_t)(c0 + sc1) * EMB + k0 + sk * 4];
  const int wo0 = sc0 * 32 + 4 * (sk ^ ((sc0 >> 2) & 7));
  const int wo1 = sc1 * 32 + 4 * (sk ^ ((sc1 >> 2) & 7));

  const float* xbase = X + (size_t)rbase * EMB + k0;

  float4 s0 = *(const float4*)(wsrc0);
  float4 s1 = *(const float4*)(wsrc1);
  *(float4*)&wt[0][wo0] = s0;
  *(float4*)&wt[0][wo1] = s1;
  float4 n0 = *(const float4*)(wsrc0 + 32);
  float4 n1 = *(const float4*)(wsrc1 + 32);
  __syncthreads();

  for (int t = 0; t < 8; ++t) {
    const int buf = t & 1;
    const float* wb = &wt[buf][0];
    const int xoff = t * 32;
#pragma unroll
    for (int k4 = 0; k4 < 8; ++k4) {
      float4 xv[8];
#pragma unroll
      for (int i = 0; i < 8; ++i)
        xv[i] = *(const float4*)&xbase[(size_t)i * EMB + xoff + k4 * 4];
      float4 wv[4];
#pragma unroll
      for (int c = 0; c < 4; ++c)
        wv[c] = *(const float4*)&wb[(4 * colg + c) * 32 + 4 * (k4 ^ perm)];
#pragma unroll
      for (int i = 0; i < 8; ++i)
#pragma unroll
        for (int c = 0; c < 4; ++c)
          acc[i][c] = fmaf(xv[i].w, wv[c].w,
                      fmaf(xv[i].z, wv[c].z,
                      fmaf(xv[i].y, wv[c].y,
                      fmaf(xv[i].x, wv[c].x, acc[i][c]))));
    }
    if (t < 7) {
      *(float4*)&wt[buf ^ 1][wo0] = n0;
      *(float4*)&wt[buf ^ 1][wo1] = n1;
      if (t < 6) {
        n0 = *(const float4*)(wsrc0 + (t + 2) * 32);
        n1 = *(const float4*)(wsrc1 + (t + 2) * 32);
      }
    }
    __syncthreads();
  }

  float* yout = Yp + ((size_t)(z * 8 + kp) * MROWS + rbase) * EMB + c0 + colg * 4;
#pragma unroll
  for (int i = 0; i < 8; ++i)
    *(float4*)&yout[(size_t)i * EMB] =
        make_float4(acc[i][0], acc[i][1], acc[i][2], acc[i][3]);
}

// ---------------------------------------------------------------------------
// Sum 8 split-K parts per matrix; apply RoPE to q,k (z=0,1); v plain.
// ---------------------------------------------------------------------------
__global__ __launch_bounds__(256) void sum_qkv_rope_k(
    const float* __restrict__ parts, float* __restrict__ yq,
    float* __restrict__ yk, float* __restrict__ yv) {
  const int idx4 = blockIdx.x * 256 + threadIdx.x;
  const int idx = idx4 << 2;
  const int row = idx >> 11;
  const int col = idx & 2047;
  const float s = (float)(row & 15);
  const int hd = col & 127;
  const float a0 = s * powf(10000.0f, -(float)hd * (1.0f / 128.0f));
  const float a1 = s * powf(10000.0f, -(float)(hd + 2) * (1.0f / 128.0f));
  float sn0, cs0, sn1, cs1;
  sincosf(a0, &sn0, &cs0);
  sincosf(a1, &sn1, &cs1);
  const float4* p = (const float4*)parts;
  float* outs[3] = {yq, yk, yv};
#pragma unroll
  for (int z = 0; z < 3; ++z) {
    float4 v = make_float4(0.f, 0.f, 0.f, 0.f);
#pragma unroll
    for (int k = 0; k < 8; ++k) {
      float4 a = p[((size_t)(z * 8 + k)) * 65536 + idx4];
      v.x += a.x; v.y += a.y; v.z += a.z; v.w += a.w;
    }
    if (z < 2) {
      float4 r;
      r.x = v.x * cs0 - v.y * sn0;
      r.y = v.x * sn0 + v.y * cs0;
      r.z = v.z * cs1 - v.w * sn1;
      r.w = v.z * sn1 + v.w * cs1;
      v = r;
    }
    ((float4*)outs[z])[idx4] = v;
  }
}

// ---------------------------------------------------------------------------
// sum 8 split-K parts + bias -> final output
// ---------------------------------------------------------------------------
__global__ __launch_bounds__(256) void sum8_bias_k(const float* __restrict__ parts,
                                                   const float* __restrict__ bo,
                                                   float* __restrict__ out) {
  const size_t idx = (size_t)blockIdx.x * 256 + threadIdx.x;
  float4 s = *(const float4*)&bo[(idx << 2) & 2047];
  const float4* p = (const float4*)parts;
#pragma unroll
  for (int k = 0; k < 8; ++k) {
    float4 v = p[(size_t)k * 65536 + idx];
    s.x += v.x; s.y += v.y; s.z += v.z; s.w += v.w;
  }
  ((float4*)out)[idx] = s;
}

// ---------------------------------------------------------------------------
// Flash-decoding attention partial. Grid (KSPLIT, NH, BATCH), 256 threads.
// Wave = 4 q-rows. Lane = (kslot 0..7: keys kslot+8i, g 0..7: d-slice 16g..+15).
// Q pre-scaled in registers (64 regs). K/V staged to XOR-swizzled LDS
// (slot = chunk ^ (row&7); reads 2-way = conflict-free). acc[4][16]=64 regs;
// scores reduced over g via shfl_xor(8,16,32); acc reduced over kslot at end.
// Tile-aligned K-split: 33 tiles of 64 keys distributed over 8 parts.
// ---------------------------------------------------------------------------
__global__ __launch_bounds__(256, 2) void attn_partial_k(
    const float* __restrict__ q, const float* __restrict__ knew,
    const float* __restrict__ vnew, const float* __restrict__ ck,
    const float* __restrict__ cv, const int* __restrict__ sp_ptr,
    float* __restrict__ po, float* __restrict__ pm, float* __restrict__ pl) {
  const int j = blockIdx.x, h = blockIdx.y, b = blockIdx.z;
  const int tid = threadIdx.x;
  const int wid = tid >> 6;   // wave: q rows 4wid..4wid+3
  const int lane = tid & 63;
  const int kslot = lane & 7;
  const int g = lane >> 3;
  const int sp = *sp_ptr;
  const int L = sp + SEQ;
  const int nTiles = (L + 63) >> 6;
  const int tA = (nTiles * j) >> 3;
  const int tB = (nTiles * (j + 1)) >> 3;

  __shared__ float kt[64 * 128];
  __shared__ float vt[64 * 128];

  const float qscale = 0.08838834764831845f;  // 1/sqrt(128)
  // Q in registers: 4 q-rows x 16-d slice, pre-scaled
  float4 Q[4][4];
  {
    const float* qb = q + (size_t)(b * SEQ + (wid << 2)) * EMB + h * HD + (g << 4);
#pragma unroll
    for (int qq = 0; qq < 4; ++qq)
#pragma unroll
      for (int c = 0; c < 4; ++c) {
        float4 v = *(const float4*)&qb[(size_t)qq * EMB + (c << 2)];
        v.x *= qscale; v.y *= qscale; v.z *= qscale; v.w *= qscale;
        Q[qq][c] = v;
      }
  }

  float acc[4][16];
#pragma unroll
  for (int qq = 0; qq < 4; ++qq)
#pragma unroll
    for (int d = 0; d < 16; ++d) acc[qq][d] = 0.f;
  float m[4] = {-1e30f, -1e30f, -1e30f, -1e30f};
  float l[4] = {0.f, 0.f, 0.f, 0.f};

  for (int t = tA; t < tB; ++t) {
    const int t0 = t << 6;
    __syncthreads();  // previous tile's reads done
    // ---- stage K,V tile into swizzled LDS ----
#pragma unroll
    for (int i = 0; i < 8; ++i) {
      int p = (i << 8) + tid;
      int row = p >> 5, c = p & 31;
      int gk = t0 + row;
      int gkE = min(gk, L - 1);
      const float *skp, *svp;
      if (gkE < sp) {
        size_t off = ((size_t)b * KVLEN + gkE) * EMB + h * HD + ((size_t)c << 2);
        skp = ck + off; svp = cv + off;
      } else {
        size_t off = ((size_t)b * SEQ + (gkE - sp)) * EMB + h * HD + ((size_t)c << 2);
        skp = knew + off; svp = vnew + off;
      }
      float4 kv4 = *(const float4*)skp;
      float4 vv4 = *(const float4*)svp;
      int slot = c ^ (row & 7);
      *(float4*)&kt[(row << 7) + (slot << 2)] = kv4;
      *(float4*)&vt[(row << 7) + (slot << 2)] = vv4;
    }
    __syncthreads();

    // ---- scores: 8 keys x 4 q, 16-d partial dots ----
    float p8[4][8];
#pragma unroll
    for (int i = 0; i < 8; ++i) {
      const int row = kslot + (i << 3);
      const int rb = row << 7;
      float4 K4[4];
#pragma unroll
      for (int c = 0; c < 4; ++c) {
        int slot = ((g << 2) + c) ^ kslot;
        K4[c] = *(const float4*)&kt[rb + (slot << 2)];
      }
#pragma unroll
      for (int qq = 0; qq < 4; ++qq)
        p8[qq][i] = dot4(K4[0], Q[qq][0]) + dot4(K4[1], Q[qq][1]) +
                    dot4(K4[2], Q[qq][2]) + dot4(K4[3], Q[qq][3]);
    }
    // ---- reduce over g (lane bits 3..5), mask tail ----
#pragma unroll
    for (int qq = 0; qq < 4; ++qq)
#pragma unroll
      for (int i = 0; i < 8; ++i) {
        float v = p8[qq][i];
        v += __shfl_xor(v, 8);
        v += __shfl_xor(v, 16);
        v += __shfl_xor(v, 32);
        if (t0 + kslot + (i << 3) >= L) v = -3.0e38f;
        p8[qq][i] = v;
      }
    // ---- online softmax per q-row ----
#pragma unroll
    for (int qq = 0; qq < 4; ++qq) {
      float tm = p8[qq][0];
#pragma unroll
      for (int i = 1; i < 8; ++i) tm = fmaxf(tm, p8[qq][i]);
      tm = fmaxf(tm, __shfl_xor(tm, 1));
      tm = fmaxf(tm, __shfl_xor(tm, 2));
      tm = fmaxf(tm, __shfl_xor(tm, 4));
      float mn = fmaxf(m[qq], tm);
      float sc = __expf(m[qq] - mn);
      float ls = 0.f;
#pragma unroll
      for (int i = 0; i < 8; ++i) {
        float pe = __expf(p8[qq][i] - mn);
        p8[qq][i] = pe;
        ls += pe;
      }
      ls += __shfl_xor(ls, 1);
      ls += __shfl_xor(ls, 2);
      ls += __shfl_xor(ls, 4);
      l[qq] = l[qq] * sc + ls;
      m[qq] = mn;
#pragma unroll
      for (int d = 0; d < 16; ++d) acc[qq][d] *= sc;
    }
    // ---- PV: accumulate this lane's 8 keys into its 16-d slice ----
#pragma unroll
    for (int i = 0; i < 8; ++i) {
      const int row = kslot + (i << 3);
      const int rb = row << 7;
      float4 V4[4];
#pragma unroll
      for (int c = 0; c < 4; ++c) {
        int slot = ((g << 2) + c) ^ kslot;
        V4[c] = *(const float4*)&vt[rb + (slot << 2)];
      }
#pragma unroll
      for (int qq = 0; qq < 4; ++qq) {
        float pv = p8[qq][i];
#pragma unroll
        for (int c = 0; c < 4; ++c) {
          acc[qq][(c << 2) + 0] = fmaf(pv, V4[c].x, acc[qq][(c << 2) + 0]);
          acc[qq][(c << 2) + 1] = fmaf(pv, V4[c].y, acc[qq][(c << 2) + 1]);
          acc[qq][(c << 2) + 2] = fmaf(pv, V4[c].z, acc[qq][(c << 2) + 2]);
          acc[qq][(c << 2) + 3] = fmaf(pv, V4[c].w, acc[qq][(c << 2) + 3]);
        }
      }
    }
  }

  // ---- reduce acc over kslot lanes; write partials ----
#pragma unroll
  for (int qq = 0; qq < 4; ++qq)
#pragma unroll
    for (int d = 0; d < 16; ++d) {
      float v = acc[qq][d];
      v += __shfl_xor(v, 1);
      v += __shfl_xor(v, 2);
      v += __shfl_xor(v, 4);
      acc[qq][d] = v;
    }
  const size_t pair = (size_t)(b * NH + h);
  const size_t pb = (pair * KSPLIT + j) * SEQ + (wid << 2);
  if (kslot == 0) {
#pragma unroll
    for (int qq = 0; qq < 4; ++qq)
#pragma unroll
      for (int c = 0; c < 4; ++c)
        *(float4*)&po[(pb + qq) * HD + (g << 4) + (c << 2)] =
            make_float4(acc[qq][(c << 2)], acc[qq][(c << 2) + 1],
                        acc[qq][(c << 2) + 2], acc[qq][(c << 2) + 3]);
  }
  if (lane == 0) {
#pragma unroll
    for (int qq = 0; qq < 4; ++qq) {
      pm[pb + qq] = m[qq];
      pl[pb + qq] = l[qq];
    }
  }
}

// ---------------------------------------------------------------------------
// Combine KSPLIT partials -> attention output (B,S,H*D) row-major.
// ---------------------------------------------------------------------------
__global__ __launch_bounds__(256) void combine_k(const float* __restrict__ po,
                                                 const float* __restrict__ pm,
                                                 const float* __restrict__ pl,
                                                 float* __restrict__ attn) {
  const int pair = blockIdx.x;
  const int b = pair >> 4, h = pair & 15;
  const int tid = threadIdx.x;
  const int d = tid & 127, gq = tid >> 7;
#pragma unroll
  for (int qi = 0; qi < 8; ++qi) {
    int qq = gq * 8 + qi;
    float mj[KSPLIT], lj[KSPLIT];
    float Mx = -1e30f;
#pragma unroll
    for (int jj = 0; jj < KSPLIT; ++jj) {
      mj[jj] = pm[((size_t)pair * KSPLIT + jj) * SEQ + qq];
      lj[jj] = pl[((size_t)pair * KSPLIT + jj) * SEQ + qq];
      Mx = fmaxf(Mx, mj[jj]);
    }
    float Ls = 0.f, o = 0.f;
#pragma unroll
    for (int jj = 0; jj < KSPLIT; ++jj) {
      float w = __expf(mj[jj] - Mx);
      Ls += lj[jj] * w;
      o += po[(((size_t)pair * KSPLIT + jj) * SEQ + qq) * HD + d] * w;
    }
    attn[(size_t)(b * SEQ + qq) * EMB + h * HD + d] = o / Ls;
  }
}

// ---------------------------------------------------------------------------
extern "C" void kernel_launch(void* const* d_in, const int* in_sizes, int n_in,
                              void* d_out, int out_size, void* d_ws,
                              size_t ws_size, hipStream_t stream) {
  const float* x = (const float*)d_in[0];
  const float* Wq = (const float*)d_in[1];
  const float* Wk = (const float*)d_in[2];
  const float* Wv = (const float*)d_in[3];
  const float* Wo = (const float*)d_in[4];
  const float* bo = (const float*)d_in[5];
  const float* ck = (const float*)d_in[6];
  const float* cv = (const float*)d_in[7];
  const int* sp = (const int*)d_in[8];
  float* out = (float*)d_out;

  float* ws = (float*)d_ws;
  const size_t U = 262144;  // 128*2048 floats
  float* yq = ws;
  float* yk = ws + U * 1;
  float* yv = ws + U * 2;
  float* attn = ws + U * 3;
  float* qkvParts = ws + U * 4;   // 3 mats x 8 parts -> [4,28)
  float* woParts = ws + U * 28;   // 8 parts -> [28,36)
  float* po = ws + U * 36;        // [36,44)
  float* pm = ws + U * 44;
  float* pl = ws + U * 44 + 16384;

  // 1) QKV projection, split-K=8
  gemm_f32<<<dim3(32, 8, 3), 256, 0, stream>>>(x, Wq, Wk, Wv, qkvParts);

  // 2) sum parts + RoPE on q,k
  sum_qkv_rope_k<<<dim3(256), 256, 0, stream>>>(qkvParts, yq, yk, yv);

  // 3) flash-decoding attention partials
  attn_partial_k<<<dim3(KSPLIT, NH, BATCH), 256, 0, stream>>>(
      yq, yk, yv, ck, cv, sp, po, pm, pl);

  // 4) combine -> attn (row-major)
  combine_k<<<dim3(BATCH * NH), 256, 0, stream>>>(po, pm, pl, attn);

  // 5) output projection, split-K=8
  gemm_f32<<<dim3(32, 8, 1), 256, 0, stream>>>(attn, Wo, Wo, Wo, woParts);

  // 6) sum parts + bias -> out
  sum8_bias_k<<<dim3(256), 256, 0, stream>>>(woParts, bo, out);

  (void)in_sizes; (void)n_in; (void)out_size; (void)ws_size;
}